// Round 6
// baseline (287.043 us; speedup 1.0000x reference)
//
#include <hip/hip_runtime.h>

#define TT 4096
#define CC 1024
#define DD 128

typedef __attribute__((ext_vector_type(8))) short s16x8;
typedef __attribute__((ext_vector_type(4))) short s16x4;
typedef __attribute__((ext_vector_type(8))) __bf16 bf16x8;
typedef __attribute__((ext_vector_type(4))) float f32x4;

__device__ __forceinline__ short f2bf(float f) {
    union { float f; unsigned u; } v; v.f = f;
    unsigned r = v.u + 0x7fffu + ((v.u >> 16) & 1u);
    return (short)(r >> 16);
}

__device__ __forceinline__ unsigned cvt_pk(float lo, float hi) {
    unsigned r;
    asm("v_cvt_pk_bf16_f32 %0, %1, %2" : "=v"(r) : "v"(lo), "v"(hi));
    return r;
}

__device__ __forceinline__ f32x4 mfma16(s16x8 a, s16x8 b, f32x4 c) {
    return __builtin_amdgcn_mfma_f32_16x16x32_bf16(
        __builtin_bit_cast(bf16x8, a), __builtin_bit_cast(bf16x8, b), c, 0, 0, 0);
}

__device__ __forceinline__ void gload_lds16(const short* g, short* l) {
    __builtin_amdgcn_global_load_lds(
        (const __attribute__((address_space(1))) void*)g,
        (__attribute__((address_space(3))) void*)l, 16, 0, 0);
}

// ---------------- kernel 0: transpose weights -> wT bf16 [3][D][C], scale wq ----
__global__ void wt_kernel(const float* __restrict__ wq, const float* __restrict__ wk,
                          const float* __restrict__ wv, short* __restrict__ wT) {
    int idx = blockIdx.x * 256 + threadIdx.x;   // 3*128*1024 = 393216 threads
    int d = idx & 127;
    int c = (idx >> 7) & 1023;
    int wsel = idx >> 17;
    const float* w = (wsel == 0) ? wq : (wsel == 1) ? wk : wv;
    float v = w[(size_t)c * DD + d];
    if (wsel == 0) v *= 0.08838834764831845f;   // D^-0.5 folded into Q
    wT[(size_t)wsel * DD * CC + (size_t)d * CC + c] = f2bf(v);
}

// ---------------- kernel 1: fused QKV projection GEMM (unchanged) ----------------
__global__ __launch_bounds__(512)
void qkv_kernel(const float* __restrict__ x, const short* __restrict__ wT,
                short* __restrict__ qo, short* __restrict__ ko, short* __restrict__ vTo) {
    __shared__ short lw[2][384 * 64];   // 2 x 48KB
    const int mt = blockIdx.x;
    const int tid = threadIdx.x, lane = tid & 63, wid = tid >> 6;
    const int l15 = lane & 15, g = lane >> 4;
    const int wm = wid >> 1, wn = wid & 1;
    const int arow = mt * 128 + wm * 32 + l15;
    const float* xr0 = x + (size_t)arow * CC + g * 8;
    const float* xr1 = xr0 + (size_t)16 * CC;

    const f32x4 fz = {0.f, 0.f, 0.f, 0.f};
    f32x4 acc[2][12];
#pragma unroll
    for (int mr = 0; mr < 2; mr++)
#pragma unroll
        for (int nr = 0; nr < 12; nr++) acc[mr][nr] = fz;

    const int swr = wid * 48;
    const short* wsrc = wT + (size_t)(swr + (lane >> 3)) * CC + (lane & 7) * 8;

    float4 pa[2][2][2];
#define LOADA(kc) do { \
    _Pragma("unroll") for (int mr_ = 0; mr_ < 2; mr_++) \
    _Pragma("unroll") for (int ks_ = 0; ks_ < 2; ks_++) { \
        const float* p_ = (mr_ ? xr1 : xr0) + (kc) * 64 + ks_ * 32; \
        pa[mr_][ks_][0] = *(const float4*)p_; \
        pa[mr_][ks_][1] = *(const float4*)(p_ + 4); } \
} while (0)
#define STAGEW(kc, buf) do { \
    _Pragma("unroll") for (int j_ = 0; j_ < 6; j_++) \
        gload_lds16(wsrc + (size_t)(j_ * 8) * CC + (kc) * 64, &lw[buf][(swr + j_ * 8) * 64]); \
} while (0)

    LOADA(0);
    STAGEW(0, 0);
    asm volatile("s_waitcnt vmcnt(0)" ::: "memory");
    __builtin_amdgcn_s_barrier();
    int cur = 0;

    for (int kc = 0; kc < 16; kc++) {
        s16x8 af[2][2];
#pragma unroll
        for (int mr = 0; mr < 2; mr++)
#pragma unroll
            for (int ks = 0; ks < 2; ks++) {
                union { unsigned u[4]; s16x8 v; } cv;
                cv.u[0] = cvt_pk(pa[mr][ks][0].x, pa[mr][ks][0].y);
                cv.u[1] = cvt_pk(pa[mr][ks][0].z, pa[mr][ks][0].w);
                cv.u[2] = cvt_pk(pa[mr][ks][1].x, pa[mr][ks][1].y);
                cv.u[3] = cvt_pk(pa[mr][ks][1].z, pa[mr][ks][1].w);
                af[mr][ks] = cv.v;
            }
        if (kc < 15) { LOADA(kc + 1); STAGEW(kc + 1, cur ^ 1); }
        __builtin_amdgcn_s_setprio(1);
#pragma unroll
        for (int ks = 0; ks < 2; ks++)
#pragma unroll
            for (int nr = 0; nr < 12; nr++) {
                const s16x8 bfg = *(const s16x8*)
                    &lw[cur][(wn * 192 + nr * 16 + l15) * 64 + ks * 32 + g * 8];
                acc[0][nr] = mfma16(af[0][ks], bfg, acc[0][nr]);
                acc[1][nr] = mfma16(af[1][ks], bfg, acc[1][nr]);
            }
        __builtin_amdgcn_s_setprio(0);
        asm volatile("s_waitcnt vmcnt(0) lgkmcnt(0)" ::: "memory");
        __builtin_amdgcn_s_barrier();
        cur ^= 1;
    }

    const int bidx = mt >> 5;
    const int tb = (mt & 31) * 128 + wm * 32;
#pragma unroll
    for (int mr = 0; mr < 2; mr++)
#pragma unroll
        for (int nr = 0; nr < 12; nr++) {
            const int n = wn * 192 + nr * 16 + l15;
            if (n < 256) {
                short* dst; int d;
                if (n < 128) { dst = qo; d = n; } else { dst = ko; d = n - 128; }
#pragma unroll
                for (int i = 0; i < 4; i++) {
                    int t = tb + mr * 16 + g * 4 + i;
                    dst[((size_t)bidx * TT + t) * DD + d] = f2bf(acc[mr][nr][i]);
                }
            } else {
                const int d = n - 256;
                const int t = tb + mr * 16 + g * 4;
                uint2 u;
                u.x = cvt_pk(acc[mr][nr][0], acc[mr][nr][1]);
                u.y = cvt_pk(acc[mr][nr][2], acc[mr][nr][3]);
                *(uint2*)(vTo + ((size_t)bidx * DD + d) * TT + t) = u;   // V^T
            }
        }
}

// ---------------- kernel 2: barrier-free L2-direct causal flash attention --------
// 256 blocks x 256 threads (4 waves). b = id&7 (one batch per XCD -> K/V L2-
// resident), pg = id>>3. Wave w handles q-subtile s1 = pg*4+w then its mirror
// 255-s1 SEQUENTIALLY -> exactly 65 kv-tile iters per wave, perfectly uniform.
// K/V fragments are read global->reg (VMEM pipe, L1/L2-served), K(t+1) and V(t)
// prefetched under compute. LDS holds only the per-wave P round-trip. No
// __syncthreads anywhere.
__global__ __launch_bounds__(256)
void attn_kernel(const short* __restrict__ qb, const short* __restrict__ kb,
                 const short* __restrict__ vb, float* __restrict__ out) {
    __shared__ short lp[4][1024];   // per-wave P [16 q][64 k] bf16, swizzled (2KB)
    const int id = blockIdx.x;
    const int b = id & 7;
    const int pg = id >> 3;         // 0..31
    const int tid = threadIdx.x, lane = tid & 63, wid = tid >> 6;
    const int l15 = lane & 15, g = lane >> 4;
    const short* kT = kb + (size_t)b * TT * DD;
    const short* vT = vb + (size_t)b * DD * TT;
    char* lpw = (char*)&lp[wid][0];
    const f32x4 fz = {0.f, 0.f, 0.f, 0.f};

    for (int ph = 0; ph < 2; ph++) {
        const int s1 = pg * 4 + wid;           // 0..127
        const int s = ph ? 255 - s1 : s1;      // this phase's q-subtile
        const int tq = s >> 2;                 // last kv tile (diagonal)
        const int wq0 = s * 16;

        s16x8 qf[4];
        {
            const short* qp = qb + ((size_t)b * TT + wq0 + l15) * DD + g * 8;
#pragma unroll
            for (int ks = 0; ks < 4; ks++) qf[ks] = *(const s16x8*)(qp + ks * 32);
        }
        f32x4 o[8];
#pragma unroll
        for (int n = 0; n < 8; n++) o[n] = fz;
        float rmax = -1e30f, rsum = 0.f;

        // prologue: K fragments for t=0
        s16x8 kreg[4][4];
#pragma unroll
        for (int sub = 0; sub < 4; sub++)
#pragma unroll
            for (int ks = 0; ks < 4; ks++)
                kreg[sub][ks] = *(const s16x8*)
                    (kT + (size_t)(sub * 16 + l15) * DD + ks * 32 + g * 8);

        for (int t = 0; t <= tq; t++) {
            const int kv0 = t * 64;
            // issue V(t) fragment loads early (consumed by PV at iter end)
            s16x8 vreg[8][2];
#pragma unroll
            for (int n = 0; n < 8; n++)
#pragma unroll
                for (int ks2 = 0; ks2 < 2; ks2++)
                    vreg[n][ks2] = *(const s16x8*)
                        (vT + (size_t)(n * 16 + l15) * TT + kv0 + ks2 * 32 + g * 8);

            // S^T = K Q^T from kreg: s[sub][i] = S[k=kv0+sub*16+4g+i][q=wq0+l15]
            f32x4 s[4];
            __builtin_amdgcn_s_setprio(1);
#pragma unroll
            for (int sub = 0; sub < 4; sub++) {
                f32x4 a = fz;
#pragma unroll
                for (int ks = 0; ks < 4; ks++)
                    a = mfma16(kreg[sub][ks], qf[ks], a);
                s[sub] = a;
            }
            __builtin_amdgcn_s_setprio(0);
            if (t == tq) {   // causal mask on the diagonal supertile
#pragma unroll
                for (int sub = 0; sub < 4; sub++)
#pragma unroll
                    for (int i = 0; i < 4; i++) {
                        int k = kv0 + sub * 16 + 4 * g + i;
                        if (k > wq0 + l15) s[sub][i] = -1e30f;
                    }
            }
            // online softmax, lane-local q-row (spread over 4 lane-groups)
            float m0 = s[0][0];
#pragma unroll
            for (int sub = 0; sub < 4; sub++)
#pragma unroll
                for (int i = 0; i < 4; i++) m0 = fmaxf(m0, s[sub][i]);
            m0 = fmaxf(m0, __shfl_xor(m0, 16));
            m0 = fmaxf(m0, __shfl_xor(m0, 32));
            float mnew = fmaxf(rmax, m0);
            float scal = __expf(rmax - mnew);
            rmax = mnew;
            float ls = 0.f;
#pragma unroll
            for (int sub = 0; sub < 4; sub++)
#pragma unroll
                for (int i = 0; i < 4; i++) {
                    float pv = __expf(s[sub][i] - mnew);
                    s[sub][i] = pv;
                    ls += pv;
                }
            ls += __shfl_xor(ls, 16);
            ls += __shfl_xor(ls, 32);
            rsum = rsum * scal + ls;

            // prefetch K(t+1) into kreg (QK already consumed it this iter)
            if (t < tq) {
#pragma unroll
                for (int sub = 0; sub < 4; sub++)
#pragma unroll
                    for (int ks = 0; ks < 4; ks++)
                        kreg[sub][ks] = *(const s16x8*)
                            (kT + (size_t)(kv0 + 64 + sub * 16 + l15) * DD + ks * 32 + g * 8);
            }

            // P -> bf16 -> LDS (per-wave, one ds_write_b64 per sub)
#pragma unroll
            for (int sub = 0; sub < 4; sub++) {
                uint2 w01;
                w01.x = cvt_pk(s[sub][0], s[sub][1]);
                w01.y = cvt_pk(s[sub][2], s[sub][3]);
                int byte = (l15 * 128 + sub * 32 + g * 8) ^ ((l15 & 7) << 4);
                *(uint2*)(lpw + byte) = w01;
            }
#pragma unroll
            for (int n = 0; n < 8; n++)
#pragma unroll
                for (int i = 0; i < 4; i++) o[n][i] *= scal;

            // PV swapped: O^T += V^T (A, rows=d, from vreg) x P^T (B, cols=q)
            __builtin_amdgcn_s_setprio(1);
#pragma unroll
            for (int ks2 = 0; ks2 < 2; ks2++) {
                int pbyte = (l15 * 128 + ks2 * 64 + g * 16) ^ ((l15 & 7) << 4);
                s16x8 pf = *(const s16x8*)(lpw + pbyte);
#pragma unroll
                for (int n = 0; n < 8; n++)
                    o[n] = mfma16(vreg[n][ks2], pf, o[n]);
            }
            __builtin_amdgcn_s_setprio(0);
        }
        // epilogue
        float inv = 1.0f / rsum;
        float* orow = out + ((size_t)b * TT + wq0 + l15) * DD;
#pragma unroll
        for (int n = 0; n < 8; n++) {
            float4 r;
            r.x = o[n][0] * inv; r.y = o[n][1] * inv;
            r.z = o[n][2] * inv; r.w = o[n][3] * inv;
            *(float4*)(orow + n * 16 + 4 * g) = r;
        }
    }
}

// ---------------- launch ---------------------------------------------------------
extern "C" void kernel_launch(void* const* d_in, const int* in_sizes, int n_in,
                              void* d_out, int out_size, void* d_ws, size_t ws_size,
                              hipStream_t stream) {
    const float* x  = (const float*)d_in[0];
    const float* wq = (const float*)d_in[1];
    const float* wk = (const float*)d_in[2];
    const float* wv = (const float*)d_in[3];
    float* out = (float*)d_out;
    char* ws = (char*)d_ws;
    short* wT = (short*)ws;
    short* qb = (short*)(ws + 786432);
    short* kb = (short*)(ws + 786432 + 8388608);
    short* vb = (short*)(ws + 786432 + 16777216);

    wt_kernel<<<1536, 256, 0, stream>>>(wq, wk, wv, wT);
    qkv_kernel<<<256, 512, 0, stream>>>(x, wT, qb, kb, vb);
    attn_kernel<<<256, 256, 0, stream>>>(qb, kb, vb, out);
}

// Round 7
// 210.036 us; speedup vs baseline: 1.3666x; 1.3666x over previous
//
#include <hip/hip_runtime.h>

#define TT 4096
#define CC 1024
#define DD 128

typedef __attribute__((ext_vector_type(8))) short s16x8;
typedef __attribute__((ext_vector_type(4))) short s16x4;
typedef __attribute__((ext_vector_type(8))) __bf16 bf16x8;
typedef __attribute__((ext_vector_type(4))) float f32x4;

__device__ __forceinline__ short f2bf(float f) {
    union { float f; unsigned u; } v; v.f = f;
    unsigned r = v.u + 0x7fffu + ((v.u >> 16) & 1u);
    return (short)(r >> 16);
}

__device__ __forceinline__ unsigned cvt_pk(float lo, float hi) {
    unsigned r;
    asm("v_cvt_pk_bf16_f32 %0, %1, %2" : "=v"(r) : "v"(lo), "v"(hi));
    return r;
}

__device__ __forceinline__ f32x4 mfma16(s16x8 a, s16x8 b, f32x4 c) {
    return __builtin_amdgcn_mfma_f32_16x16x32_bf16(
        __builtin_bit_cast(bf16x8, a), __builtin_bit_cast(bf16x8, b), c, 0, 0, 0);
}

__device__ __forceinline__ void gload_lds16(const short* g, short* l) {
    __builtin_amdgcn_global_load_lds(
        (const __attribute__((address_space(1))) void*)g,
        (__attribute__((address_space(3))) void*)l, 16, 0, 0);
}

// ---------------- kernel 0: transpose weights -> wT bf16 [3][D][C], scale wq ----
__global__ void wt_kernel(const float* __restrict__ wq, const float* __restrict__ wk,
                          const float* __restrict__ wv, short* __restrict__ wT) {
    int idx = blockIdx.x * 256 + threadIdx.x;   // 3*128*1024 = 393216 threads
    int d = idx & 127;
    int c = (idx >> 7) & 1023;
    int wsel = idx >> 17;
    const float* w = (wsel == 0) ? wq : (wsel == 1) ? wk : wv;
    float v = w[(size_t)c * DD + d];
    if (wsel == 0) v *= 0.08838834764831845f;   // D^-0.5 folded into Q
    wT[(size_t)wsel * DD * CC + (size_t)d * CC + c] = f2bf(v);
}

// ---------------- kernel 1: fused QKV projection GEMM (unchanged) ----------------
__global__ __launch_bounds__(512)
void qkv_kernel(const float* __restrict__ x, const short* __restrict__ wT,
                short* __restrict__ qo, short* __restrict__ ko, short* __restrict__ vTo) {
    __shared__ short lw[2][384 * 64];   // 2 x 48KB
    const int mt = blockIdx.x;
    const int tid = threadIdx.x, lane = tid & 63, wid = tid >> 6;
    const int l15 = lane & 15, g = lane >> 4;
    const int wm = wid >> 1, wn = wid & 1;
    const int arow = mt * 128 + wm * 32 + l15;
    const float* xr0 = x + (size_t)arow * CC + g * 8;
    const float* xr1 = xr0 + (size_t)16 * CC;

    const f32x4 fz = {0.f, 0.f, 0.f, 0.f};
    f32x4 acc[2][12];
#pragma unroll
    for (int mr = 0; mr < 2; mr++)
#pragma unroll
        for (int nr = 0; nr < 12; nr++) acc[mr][nr] = fz;

    const int swr = wid * 48;
    const short* wsrc = wT + (size_t)(swr + (lane >> 3)) * CC + (lane & 7) * 8;

    float4 pa[2][2][2];
#define LOADA(kc) do { \
    _Pragma("unroll") for (int mr_ = 0; mr_ < 2; mr_++) \
    _Pragma("unroll") for (int ks_ = 0; ks_ < 2; ks_++) { \
        const float* p_ = (mr_ ? xr1 : xr0) + (kc) * 64 + ks_ * 32; \
        pa[mr_][ks_][0] = *(const float4*)p_; \
        pa[mr_][ks_][1] = *(const float4*)(p_ + 4); } \
} while (0)
#define STAGEW(kc, buf) do { \
    _Pragma("unroll") for (int j_ = 0; j_ < 6; j_++) \
        gload_lds16(wsrc + (size_t)(j_ * 8) * CC + (kc) * 64, &lw[buf][(swr + j_ * 8) * 64]); \
} while (0)

    LOADA(0);
    STAGEW(0, 0);
    asm volatile("s_waitcnt vmcnt(0)" ::: "memory");
    __builtin_amdgcn_s_barrier();
    int cur = 0;

    for (int kc = 0; kc < 16; kc++) {
        s16x8 af[2][2];
#pragma unroll
        for (int mr = 0; mr < 2; mr++)
#pragma unroll
            for (int ks = 0; ks < 2; ks++) {
                union { unsigned u[4]; s16x8 v; } cv;
                cv.u[0] = cvt_pk(pa[mr][ks][0].x, pa[mr][ks][0].y);
                cv.u[1] = cvt_pk(pa[mr][ks][0].z, pa[mr][ks][0].w);
                cv.u[2] = cvt_pk(pa[mr][ks][1].x, pa[mr][ks][1].y);
                cv.u[3] = cvt_pk(pa[mr][ks][1].z, pa[mr][ks][1].w);
                af[mr][ks] = cv.v;
            }
        if (kc < 15) { LOADA(kc + 1); STAGEW(kc + 1, cur ^ 1); }
        __builtin_amdgcn_s_setprio(1);
#pragma unroll
        for (int ks = 0; ks < 2; ks++)
#pragma unroll
            for (int nr = 0; nr < 12; nr++) {
                const s16x8 bfg = *(const s16x8*)
                    &lw[cur][(wn * 192 + nr * 16 + l15) * 64 + ks * 32 + g * 8];
                acc[0][nr] = mfma16(af[0][ks], bfg, acc[0][nr]);
                acc[1][nr] = mfma16(af[1][ks], bfg, acc[1][nr]);
            }
        __builtin_amdgcn_s_setprio(0);
        asm volatile("s_waitcnt vmcnt(0) lgkmcnt(0)" ::: "memory");
        __builtin_amdgcn_s_barrier();
        cur ^= 1;
    }

    const int bidx = mt >> 5;
    const int tb = (mt & 31) * 128 + wm * 32;
#pragma unroll
    for (int mr = 0; mr < 2; mr++)
#pragma unroll
        for (int nr = 0; nr < 12; nr++) {
            const int n = wn * 192 + nr * 16 + l15;
            if (n < 256) {
                short* dst; int d;
                if (n < 128) { dst = qo; d = n; } else { dst = ko; d = n - 128; }
#pragma unroll
                for (int i = 0; i < 4; i++) {
                    int t = tb + mr * 16 + g * 4 + i;
                    dst[((size_t)bidx * TT + t) * DD + d] = f2bf(acc[mr][nr][i]);
                }
            } else {
                const int d = n - 256;
                const int t = tb + mr * 16 + g * 4;
                uint2 u;
                u.x = cvt_pk(acc[mr][nr][0], acc[mr][nr][1]);
                u.y = cvt_pk(acc[mr][nr][2], acc[mr][nr][3]);
                *(uint2*)(vTo + ((size_t)bidx * DD + d) * TT + t) = u;   // V^T
            }
        }
}

// ---------------- kernel 2: split-pipe paired causal flash attention -------------
// 256 blocks x 512 threads (8 waves, 2/SIMD). b = id&7 (one batch per XCD ->
// K/V L2-resident), p = id>>3. Waves 0-3 own q-tile p, waves 4-7 own 63-p
// (per-SIMD work = 65 wave-iters on every block -> balanced).
// Pipe split: K -> registers direct from global (prefetched a FULL iter ahead,
// never drained: counted vmcnt keeps it in flight across the barrier);
// V -> LDS via global_load_lds (multicast to 4 waves); P -> tiny LDS roundtrip.
__device__ __forceinline__ void stage_v(const short* vT, int kv0, short* lvb,
                                        int wid, int lane) {
#pragma unroll
    for (int j = 0; j < 2; j++) {
        int rbv = wid * 16 + j * 8;                // 16 d-rows per wave
        int dv = rbv + (lane >> 3);
        int cv = (lane & 7) ^ (dv & 7);            // pre-swizzled global source
        gload_lds16(vT + (size_t)dv * TT + kv0 + cv * 8, lvb + rbv * 64);
    }
}

__global__ __launch_bounds__(512)
void attn_kernel(const short* __restrict__ qb, const short* __restrict__ kb,
                 const short* __restrict__ vb, float* __restrict__ out) {
    __shared__ short lv[2][128 * 64];   // 32KB V^T tiles (dbuf)
    __shared__ short lp[8][1024];       // 16KB P per wave [16 q][64 k]
    const int id = blockIdx.x;
    const int b = id & 7;
    const int p = id >> 3;              // 0..31
    const int tid = threadIdx.x, lane = tid & 63, wid = tid >> 6;
    const int l15 = lane & 15, g = lane >> 4;
    const int qt_w = (wid < 4) ? p : 63 - p;       // this wave's q-tile
    const int wq0 = qt_w * 64 + (wid & 3) * 16;    // this wave's 16 q-rows
    const int tmax = 63 - p;                       // block's last kv tile
    const short* kT = kb + (size_t)b * TT * DD;
    const short* vT = vb + (size_t)b * DD * TT;
    char* lpw = (char*)&lp[wid][0];
    const f32x4 fz = {0.f, 0.f, 0.f, 0.f};

    s16x8 qf[4];
    {
        const short* qp = qb + ((size_t)b * TT + wq0 + l15) * DD + g * 8;
#pragma unroll
        for (int ks = 0; ks < 4; ks++) qf[ks] = *(const s16x8*)(qp + ks * 32);
    }
    f32x4 o[8];
#pragma unroll
    for (int n = 0; n < 8; n++) o[n] = fz;
    float rmax = -1e30f, rsum = 0.f;

    // K fragments, register-resident, refilled one tile ahead
    s16x8 kreg[4][4];
#define LOADK(kv0) do { \
    _Pragma("unroll") for (int sub_ = 0; sub_ < 4; sub_++) \
    _Pragma("unroll") for (int ks_ = 0; ks_ < 4; ks_++) \
        kreg[sub_][ks_] = *(const s16x8*) \
            (kT + (size_t)((kv0) + sub_ * 16 + l15) * DD + ks_ * 32 + g * 8); \
} while (0)

    LOADK(0);
    stage_v(vT, 0, lv[0], wid, lane);
    asm volatile("s_waitcnt vmcnt(0)" ::: "memory");
    __builtin_amdgcn_s_barrier();
    int cur = 0;

    for (int t = 0; t <= tmax; t++) {
        if (t < tmax) stage_v(vT, (t + 1) * 64, lv[cur ^ 1], wid, lane);
        asm volatile("" ::: "memory");   // pin: V-stage issues before kreg loads
        if (t <= qt_w) {                 // wave-uniform activity test
            const int kv0 = t * 64;
            // S^T = K Q^T from kreg: s[sub][i] = S[k=kv0+sub*16+4g+i][q=wq0+l15]
            f32x4 s[4];
            __builtin_amdgcn_s_setprio(1);
#pragma unroll
            for (int sub = 0; sub < 4; sub++) {
                f32x4 a = fz;
#pragma unroll
                for (int ks = 0; ks < 4; ks++)
                    a = mfma16(kreg[sub][ks], qf[ks], a);
                s[sub] = a;
            }
            __builtin_amdgcn_s_setprio(0);
            // refill kreg for t+1 (QK above already consumed current tile)
            if (t < qt_w) LOADK((t + 1) * 64);
            if (t == qt_w) {             // causal mask on diagonal supertile
#pragma unroll
                for (int sub = 0; sub < 4; sub++)
#pragma unroll
                    for (int i = 0; i < 4; i++) {
                        int k = kv0 + sub * 16 + 4 * g + i;
                        if (k > wq0 + l15) s[sub][i] = -1e30f;
                    }
            }
            // online softmax, lane-local q-row
            float m0 = s[0][0];
#pragma unroll
            for (int sub = 0; sub < 4; sub++)
#pragma unroll
                for (int i = 0; i < 4; i++) m0 = fmaxf(m0, s[sub][i]);
            m0 = fmaxf(m0, __shfl_xor(m0, 16));
            m0 = fmaxf(m0, __shfl_xor(m0, 32));
            float mnew = fmaxf(rmax, m0);
            float scal = __expf(rmax - mnew);
            rmax = mnew;
            float ls = 0.f;
#pragma unroll
            for (int sub = 0; sub < 4; sub++)
#pragma unroll
                for (int i = 0; i < 4; i++) {
                    float pv = __expf(s[sub][i] - mnew);
                    s[sub][i] = pv;
                    ls += pv;
                }
            ls += __shfl_xor(ls, 16);
            ls += __shfl_xor(ls, 32);
            rsum = rsum * scal + ls;
            // P -> bf16 -> LDS (one ds_write_b64 per sub)
#pragma unroll
            for (int sub = 0; sub < 4; sub++) {
                uint2 w01;
                w01.x = cvt_pk(s[sub][0], s[sub][1]);
                w01.y = cvt_pk(s[sub][2], s[sub][3]);
                int byte = (l15 * 128 + sub * 32 + g * 8) ^ ((l15 & 7) << 4);
                *(uint2*)(lpw + byte) = w01;
            }
#pragma unroll
            for (int n = 0; n < 8; n++)
#pragma unroll
                for (int i = 0; i < 4; i++) o[n][i] *= scal;
            // PV swapped: O^T += V^T (A, rows=d, LDS) x P^T (B, cols=q)
            __builtin_amdgcn_s_setprio(1);
#pragma unroll
            for (int ks2 = 0; ks2 < 2; ks2++) {
                int pbyte = (l15 * 128 + ks2 * 64 + g * 16) ^ ((l15 & 7) << 4);
                s16x8 pf = *(const s16x8*)(lpw + pbyte);
#pragma unroll
                for (int n = 0; n < 8; n++) {
                    int vrow = n * 16 + l15;
                    int vbyte = (vrow * 128 + ks2 * 64 + g * 16) ^ ((vrow & 7) << 4);
                    s16x8 vf = *(const s16x8*)((const char*)&lv[cur][0] + vbyte);
                    o[n] = mfma16(vf, pf, o[n]);
                }
            }
            __builtin_amdgcn_s_setprio(0);
        }
        // drain ONLY this iter's V-stage: it is the oldest VMEM; the 16 kreg
        // prefetch loads (if issued) stay in flight across the barrier.
        if (t < qt_w) asm volatile("s_waitcnt vmcnt(16)" ::: "memory");
        else          asm volatile("s_waitcnt vmcnt(0)"  ::: "memory");
        __builtin_amdgcn_s_barrier();
        cur ^= 1;
    }
    float inv = 1.0f / rsum;
    float* orow = out + ((size_t)b * TT + wq0 + l15) * DD;
#pragma unroll
    for (int n = 0; n < 8; n++) {
        float4 r;
        r.x = o[n][0] * inv; r.y = o[n][1] * inv;
        r.z = o[n][2] * inv; r.w = o[n][3] * inv;
        *(float4*)(orow + n * 16 + 4 * g) = r;
    }
}

// ---------------- launch ---------------------------------------------------------
extern "C" void kernel_launch(void* const* d_in, const int* in_sizes, int n_in,
                              void* d_out, int out_size, void* d_ws, size_t ws_size,
                              hipStream_t stream) {
    const float* x  = (const float*)d_in[0];
    const float* wq = (const float*)d_in[1];
    const float* wk = (const float*)d_in[2];
    const float* wv = (const float*)d_in[3];
    float* out = (float*)d_out;
    char* ws = (char*)d_ws;
    short* wT = (short*)ws;
    short* qb = (short*)(ws + 786432);
    short* kb = (short*)(ws + 786432 + 8388608);
    short* vb = (short*)(ws + 786432 + 16777216);

    wt_kernel<<<1536, 256, 0, stream>>>(wq, wk, wv, wT);
    qkv_kernel<<<256, 512, 0, stream>>>(x, wT, qb, kb, vb);
    attn_kernel<<<256, 512, 0, stream>>>(qb, kb, vb, out);
}

// Round 8
// 170.689 us; speedup vs baseline: 1.6817x; 1.2305x over previous
//
#include <hip/hip_runtime.h>

#define TT 4096
#define CC 1024
#define DD 128

typedef __attribute__((ext_vector_type(8))) short s16x8;
typedef __attribute__((ext_vector_type(4))) short s16x4;
typedef __attribute__((ext_vector_type(8))) __bf16 bf16x8;
typedef __attribute__((ext_vector_type(4))) float f32x4;

__device__ __forceinline__ short f2bf(float f) {
    union { float f; unsigned u; } v; v.f = f;
    unsigned r = v.u + 0x7fffu + ((v.u >> 16) & 1u);
    return (short)(r >> 16);
}

__device__ __forceinline__ unsigned cvt_pk(float lo, float hi) {
    unsigned r;
    asm("v_cvt_pk_bf16_f32 %0, %1, %2" : "=v"(r) : "v"(lo), "v"(hi));
    return r;
}

__device__ __forceinline__ f32x4 mfma16(s16x8 a, s16x8 b, f32x4 c) {
    return __builtin_amdgcn_mfma_f32_16x16x32_bf16(
        __builtin_bit_cast(bf16x8, a), __builtin_bit_cast(bf16x8, b), c, 0, 0, 0);
}

__device__ __forceinline__ void gload_lds16(const short* g, short* l) {
    __builtin_amdgcn_global_load_lds(
        (const __attribute__((address_space(1))) void*)g,
        (__attribute__((address_space(3))) void*)l, 16, 0, 0);
}

// ---------------- kernel 0: transpose weights -> wT bf16 [3][D][C], scale wq ----
__global__ void wt_kernel(const float* __restrict__ wq, const float* __restrict__ wk,
                          const float* __restrict__ wv, short* __restrict__ wT) {
    int idx = blockIdx.x * 256 + threadIdx.x;   // 3*128*1024 = 393216 threads
    int d = idx & 127;
    int c = (idx >> 7) & 1023;
    int wsel = idx >> 17;
    const float* w = (wsel == 0) ? wq : (wsel == 1) ? wk : wv;
    float v = w[(size_t)c * DD + d];
    if (wsel == 0) v *= 0.08838834764831845f;   // D^-0.5 folded into Q
    wT[(size_t)wsel * DD * CC + (size_t)d * CC + c] = f2bf(v);
}

// ---------------- kernel 1: fused QKV projection GEMM (unchanged) ----------------
__global__ __launch_bounds__(512)
void qkv_kernel(const float* __restrict__ x, const short* __restrict__ wT,
                short* __restrict__ qo, short* __restrict__ ko, short* __restrict__ vTo) {
    __shared__ short lw[2][384 * 64];   // 2 x 48KB
    const int mt = blockIdx.x;
    const int tid = threadIdx.x, lane = tid & 63, wid = tid >> 6;
    const int l15 = lane & 15, g = lane >> 4;
    const int wm = wid >> 1, wn = wid & 1;
    const int arow = mt * 128 + wm * 32 + l15;
    const float* xr0 = x + (size_t)arow * CC + g * 8;
    const float* xr1 = xr0 + (size_t)16 * CC;

    const f32x4 fz = {0.f, 0.f, 0.f, 0.f};
    f32x4 acc[2][12];
#pragma unroll
    for (int mr = 0; mr < 2; mr++)
#pragma unroll
        for (int nr = 0; nr < 12; nr++) acc[mr][nr] = fz;

    const int swr = wid * 48;
    const short* wsrc = wT + (size_t)(swr + (lane >> 3)) * CC + (lane & 7) * 8;

    float4 pa[2][2][2];
#define LOADA(kc) do { \
    _Pragma("unroll") for (int mr_ = 0; mr_ < 2; mr_++) \
    _Pragma("unroll") for (int ks_ = 0; ks_ < 2; ks_++) { \
        const float* p_ = (mr_ ? xr1 : xr0) + (kc) * 64 + ks_ * 32; \
        pa[mr_][ks_][0] = *(const float4*)p_; \
        pa[mr_][ks_][1] = *(const float4*)(p_ + 4); } \
} while (0)
#define STAGEW(kc, buf) do { \
    _Pragma("unroll") for (int j_ = 0; j_ < 6; j_++) \
        gload_lds16(wsrc + (size_t)(j_ * 8) * CC + (kc) * 64, &lw[buf][(swr + j_ * 8) * 64]); \
} while (0)

    LOADA(0);
    STAGEW(0, 0);
    asm volatile("s_waitcnt vmcnt(0)" ::: "memory");
    __builtin_amdgcn_s_barrier();
    int cur = 0;

    for (int kc = 0; kc < 16; kc++) {
        s16x8 af[2][2];
#pragma unroll
        for (int mr = 0; mr < 2; mr++)
#pragma unroll
            for (int ks = 0; ks < 2; ks++) {
                union { unsigned u[4]; s16x8 v; } cv;
                cv.u[0] = cvt_pk(pa[mr][ks][0].x, pa[mr][ks][0].y);
                cv.u[1] = cvt_pk(pa[mr][ks][0].z, pa[mr][ks][0].w);
                cv.u[2] = cvt_pk(pa[mr][ks][1].x, pa[mr][ks][1].y);
                cv.u[3] = cvt_pk(pa[mr][ks][1].z, pa[mr][ks][1].w);
                af[mr][ks] = cv.v;
            }
        if (kc < 15) { LOADA(kc + 1); STAGEW(kc + 1, cur ^ 1); }
        __builtin_amdgcn_s_setprio(1);
#pragma unroll
        for (int ks = 0; ks < 2; ks++)
#pragma unroll
            for (int nr = 0; nr < 12; nr++) {
                const s16x8 bfg = *(const s16x8*)
                    &lw[cur][(wn * 192 + nr * 16 + l15) * 64 + ks * 32 + g * 8];
                acc[0][nr] = mfma16(af[0][ks], bfg, acc[0][nr]);
                acc[1][nr] = mfma16(af[1][ks], bfg, acc[1][nr]);
            }
        __builtin_amdgcn_s_setprio(0);
        asm volatile("s_waitcnt vmcnt(0) lgkmcnt(0)" ::: "memory");
        __builtin_amdgcn_s_barrier();
        cur ^= 1;
    }

    const int bidx = mt >> 5;
    const int tb = (mt & 31) * 128 + wm * 32;
#pragma unroll
    for (int mr = 0; mr < 2; mr++)
#pragma unroll
        for (int nr = 0; nr < 12; nr++) {
            const int n = wn * 192 + nr * 16 + l15;
            if (n < 256) {
                short* dst; int d;
                if (n < 128) { dst = qo; d = n; } else { dst = ko; d = n - 128; }
#pragma unroll
                for (int i = 0; i < 4; i++) {
                    int t = tb + mr * 16 + g * 4 + i;
                    dst[((size_t)bidx * TT + t) * DD + d] = f2bf(acc[mr][nr][i]);
                }
            } else {
                const int d = n - 256;
                const int t = tb + mr * 16 + g * 4;
                uint2 u;
                u.x = cvt_pk(acc[mr][nr][0], acc[mr][nr][1]);
                u.y = cvt_pk(acc[mr][nr][2], acc[mr][nr][3]);
                *(uint2*)(vTo + ((size_t)bidx * DD + d) * TT + t) = u;   // V^T
            }
        }
}

// ---------------- kernel 2: split-K causal flash attention -----------------------
// Block = (q-tile qt of 64 rows, kv-chunk c of <=16 tiles, batch b).
// 4 waves x 16 q-rows, ALL waves share diagonal qt -> every wave computes in
// every slot. <=16 uniform slots/block, 2 blocks/CU resident, 1280 live blocks
// dynamically refilled -> balanced makespan. Multi-chunk tiles emit partial
// (O, m, l); comb_kernel merges.
__device__ __forceinline__ void attn_stage(const short* kT, const short* vT, int kv0,
                                           short* lkb, short* lvb, int wid, int lane) {
#pragma unroll
    for (int j = 0; j < 4; j++) {
        int rbk = wid * 16 + j * 4;
        int rk = rbk + (lane >> 4);
        int ck = (lane & 15) ^ (rk & 7);
        gload_lds16(kT + (size_t)(kv0 + rk) * DD + ck * 8, lkb + rbk * 128);
        int rbv = wid * 32 + j * 8;
        int dv = rbv + (lane >> 3);
        int cv = (lane & 7) ^ (dv & 7);
        gload_lds16(vT + (size_t)dv * TT + kv0 + cv * 8, lvb + rbv * 64);
    }
}

__global__ __launch_bounds__(256)
void attn_kernel(const short* __restrict__ qb, const short* __restrict__ kb,
                 const short* __restrict__ vb, float* __restrict__ out,
                 float* __restrict__ opart, float2* __restrict__ mlpart) {
    const int qt = blockIdx.x;          // 0..63
    const int c  = blockIdx.y;          // 0..3
    const int b  = blockIdx.z;          // 0..7
    const int t0 = c * 16;
    if (t0 > qt) return;                // dead chunk: exit before any barrier
    const int t1 = (t0 + 16 < qt + 1) ? t0 + 16 : qt + 1;
    const int nc = (qt >> 4) + 1;       // chunks for this tile (1..4)

    __shared__ short lk[2][64 * 128];   // 32KB K tiles (dbuf, swizzled chunks)
    __shared__ short lv[2][128 * 64];   // 32KB V^T tiles
    __shared__ short lp[4][1024];       // 8KB P per wave
    const int tid = threadIdx.x, lane = tid & 63, wid = tid >> 6;
    const int l15 = lane & 15, g = lane >> 4;
    const int wq0 = qt * 64 + wid * 16;
    const short* kT = kb + (size_t)b * TT * DD;
    const short* vT = vb + (size_t)b * DD * TT;
    char* lpw = (char*)&lp[wid][0];
    const f32x4 fz = {0.f, 0.f, 0.f, 0.f};

    s16x8 qf[4];
    {
        const short* qp = qb + ((size_t)b * TT + wq0 + l15) * DD + g * 8;
#pragma unroll
        for (int ks = 0; ks < 4; ks++) qf[ks] = *(const s16x8*)(qp + ks * 32);
    }
    f32x4 o[8];
#pragma unroll
    for (int n = 0; n < 8; n++) o[n] = fz;
    float rmax = -1e30f, rsum = 0.f;

    attn_stage(kT, vT, t0 * 64, lk[0], lv[0], wid, lane);
    asm volatile("s_waitcnt vmcnt(0)" ::: "memory");
    __builtin_amdgcn_s_barrier();
    int cur = 0;

    for (int t = t0; t < t1; t++) {
        if (t + 1 < t1) attn_stage(kT, vT, (t + 1) * 64, lk[cur ^ 1], lv[cur ^ 1], wid, lane);
        const int kv0 = t * 64;
        const char* lkc = (const char*)&lk[cur][0];
        const char* lvc = (const char*)&lv[cur][0];

        // S^T = K Q^T : s[sub][i] = S[k=kv0+sub*16+4g+i][q=wq0+l15]
        f32x4 s[4];
        __builtin_amdgcn_s_setprio(1);
#pragma unroll
        for (int sub = 0; sub < 4; sub++) {
            f32x4 a = fz;
#pragma unroll
            for (int ks = 0; ks < 4; ks++) {
                int row = sub * 16 + l15;
                int byte = (row * 256 + ks * 64 + g * 16) ^ ((row & 7) << 4);
                s16x8 kf = *(const s16x8*)(lkc + byte);
                a = mfma16(kf, qf[ks], a);
            }
            s[sub] = a;
        }
        __builtin_amdgcn_s_setprio(0);
        if (t == qt) {                  // causal mask on diagonal supertile
#pragma unroll
            for (int sub = 0; sub < 4; sub++)
#pragma unroll
                for (int i = 0; i < 4; i++) {
                    int k = kv0 + sub * 16 + 4 * g + i;
                    if (k > wq0 + l15) s[sub][i] = -1e30f;
                }
        }
        // online softmax, lane-local q-row
        float m0 = s[0][0];
#pragma unroll
        for (int sub = 0; sub < 4; sub++)
#pragma unroll
            for (int i = 0; i < 4; i++) m0 = fmaxf(m0, s[sub][i]);
        m0 = fmaxf(m0, __shfl_xor(m0, 16));
        m0 = fmaxf(m0, __shfl_xor(m0, 32));
        float mnew = fmaxf(rmax, m0);
        float scal = __expf(rmax - mnew);
        rmax = mnew;
        float ls = 0.f;
#pragma unroll
        for (int sub = 0; sub < 4; sub++)
#pragma unroll
            for (int i = 0; i < 4; i++) {
                float pv = __expf(s[sub][i] - mnew);
                s[sub][i] = pv;
                ls += pv;
            }
        ls += __shfl_xor(ls, 16);
        ls += __shfl_xor(ls, 32);
        rsum = rsum * scal + ls;
        // P -> bf16 -> LDS (one ds_write_b64 per sub)
#pragma unroll
        for (int sub = 0; sub < 4; sub++) {
            uint2 w01;
            w01.x = cvt_pk(s[sub][0], s[sub][1]);
            w01.y = cvt_pk(s[sub][2], s[sub][3]);
            int byte = (l15 * 128 + sub * 32 + g * 8) ^ ((l15 & 7) << 4);
            *(uint2*)(lpw + byte) = w01;
        }
#pragma unroll
        for (int n = 0; n < 8; n++)
#pragma unroll
            for (int i = 0; i < 4; i++) o[n][i] *= scal;
        // PV swapped: O^T += V^T (A, rows=d, LDS) x P^T (B, cols=q)
        __builtin_amdgcn_s_setprio(1);
#pragma unroll
        for (int ks2 = 0; ks2 < 2; ks2++) {
            int pbyte = (l15 * 128 + ks2 * 64 + g * 16) ^ ((l15 & 7) << 4);
            s16x8 pf = *(const s16x8*)(lpw + pbyte);
#pragma unroll
            for (int n = 0; n < 8; n++) {
                int vrow = n * 16 + l15;
                int vbyte = (vrow * 128 + ks2 * 64 + g * 16) ^ ((vrow & 7) << 4);
                s16x8 vf = *(const s16x8*)(lvc + vbyte);
                o[n] = mfma16(vf, pf, o[n]);
            }
        }
        __builtin_amdgcn_s_setprio(0);
        asm volatile("s_waitcnt vmcnt(0) lgkmcnt(0)" ::: "memory");
        __builtin_amdgcn_s_barrier();
        cur ^= 1;
    }

    const int r = wid * 16 + l15;       // q-row within tile
    if (nc == 1) {                      // single chunk: write final output
        float inv = 1.0f / rsum;
        float* orow = out + ((size_t)b * TT + qt * 64 + r) * DD;
#pragma unroll
        for (int n = 0; n < 8; n++) {
            float4 w;
            w.x = o[n][0] * inv; w.y = o[n][1] * inv;
            w.z = o[n][2] * inv; w.w = o[n][3] * inv;
            *(float4*)(orow + n * 16 + 4 * g) = w;
        }
    } else {                            // partial: raw O + (m,l)
        const size_t pb = ((size_t)b * 48 + (qt - 16)) * 4 + c;
        float* prow = opart + pb * (64 * 128) + (size_t)r * 128;
#pragma unroll
        for (int n = 0; n < 8; n++) {
            float4 w;
            w.x = o[n][0]; w.y = o[n][1]; w.z = o[n][2]; w.w = o[n][3];
            *(float4*)(prow + n * 16 + 4 * g) = w;
        }
        if (g == 0) {
            float2 s2; s2.x = rmax; s2.y = rsum;
            mlpart[pb * 64 + r] = s2;
        }
    }
}

// ---------------- kernel 3: combine partials (qt >= 16) --------------------------
__global__ __launch_bounds__(256)
void comb_kernel(const float* __restrict__ opart, const float2* __restrict__ mlpart,
                 float* __restrict__ out) {
    const int qtm = blockIdx.x;         // 0..47 -> qt = 16 + qtm
    const int b = blockIdx.y;
    const int qt = 16 + qtm;
    const int nc = (qt >> 4) + 1;       // 2..4
    const int tid = threadIdx.x;
    const int row = tid >> 2, quad = tid & 3;
    const size_t base = ((size_t)b * 48 + qtm) * 4;

    float M = -3e38f;
    for (int cc = 0; cc < nc; cc++)
        M = fmaxf(M, mlpart[(base + cc) * 64 + row].x);

    float acc[32];                      // 8 float4s, static-indexed
#pragma unroll
    for (int k = 0; k < 32; k++) acc[k] = 0.f;
    float L = 0.f;
    for (int cc = 0; cc < nc; cc++) {
        float2 s = mlpart[(base + cc) * 64 + row];
        float wgt = __expf(s.x - M);
        L += wgt * s.y;
        const float* src = opart + (base + cc) * (64 * 128) + (size_t)row * 128 + quad * 32;
#pragma unroll
        for (int k = 0; k < 8; k++) {
            float4 v = *(const float4*)(src + k * 4);
            acc[k * 4 + 0] += wgt * v.x;
            acc[k * 4 + 1] += wgt * v.y;
            acc[k * 4 + 2] += wgt * v.z;
            acc[k * 4 + 3] += wgt * v.w;
        }
    }
    float inv = 1.0f / L;
    float* dst = out + ((size_t)b * TT + qt * 64 + row) * DD + quad * 32;
#pragma unroll
    for (int k = 0; k < 8; k++) {
        float4 w;
        w.x = acc[k * 4 + 0] * inv; w.y = acc[k * 4 + 1] * inv;
        w.z = acc[k * 4 + 2] * inv; w.w = acc[k * 4 + 3] * inv;
        *(float4*)(dst + k * 4) = w;
    }
}

// ---------------- launch ---------------------------------------------------------
extern "C" void kernel_launch(void* const* d_in, const int* in_sizes, int n_in,
                              void* d_out, int out_size, void* d_ws, size_t ws_size,
                              hipStream_t stream) {
    const float* x  = (const float*)d_in[0];
    const float* wq = (const float*)d_in[1];
    const float* wk = (const float*)d_in[2];
    const float* wv = (const float*)d_in[3];
    float* out = (float*)d_out;
    char* ws = (char*)d_ws;
    // ws: wT 768KB | q 8MB | k 8MB | vT 8MB | Opart 48MB | ML 768KB  (~74MB)
    short* wT = (short*)ws;
    short* qb = (short*)(ws + 786432);
    short* kb = (short*)(ws + 786432 + 8388608);
    short* vb = (short*)(ws + 786432 + 16777216);
    float* opart = (float*)(ws + 786432 + 25165824);
    float2* mlpart = (float2*)(ws + 786432 + 25165824 + 50331648);

    wt_kernel<<<1536, 256, 0, stream>>>(wq, wk, wv, wT);
    qkv_kernel<<<256, 512, 0, stream>>>(x, wT, qb, kb, vb);
    attn_kernel<<<dim3(64, 4, 8), 256, 0, stream>>>(qb, kb, vb, out, opart, mlpart);
    comb_kernel<<<dim3(48, 8), 256, 0, stream>>>(opart, mlpart, out);
}